// Round 7
// baseline (718.511 us; speedup 1.0000x reference)
//
#include <hip/hip_runtime.h>
#include <hip/hip_bf16.h>

#define N_B 1024
#define N_ITEMS 100000
#define N_CLUSTERS 10
#define N_D 64
#define N_JT (N_ITEMS / 16)   // 6250 j-tiles of 16 items
#define GY 98                 // j-block dimension: 98*4 waves*16 tiles >= 6250

typedef __attribute__((ext_vector_type(8))) short short8;
typedef __attribute__((ext_vector_type(4))) float f32x4;

__device__ __forceinline__ void atomAddF(float* p, float v) {
  unsafeAtomicAdd(p, v);
}

// bf16 RNE split helpers (bit-level; sign-safe)
__device__ __forceinline__ unsigned short bf16_rne(float x) {
  unsigned u = __float_as_uint(x);
  u += 0x7FFFu + ((u >> 16) & 1u);
  return (unsigned short)(u >> 16);
}
__device__ __forceinline__ float bf16_f(unsigned short b) {
  return __uint_as_float(((unsigned)b) << 16);
}

// ---------------------------------------------------------------------------
// Kernel 0 (new): stream W2 row-major (fully contiguous reads) and emit the
// packed split-bf16 buffer in EXACTLY k3's B-fragment consumption order:
//   pk[jt*1024 + s*64 + quad*16 + l15] = hi | lo<<16
// where s = (row/32)*8 + row%8, quad = (row%32)/8, col = jt*16+l15.
// Per wave, writes are 4 chunks of 64 contiguous bytes. All six prior rounds
// show strided-64B W2 walks pinned at ~180 GB/s; this kernel is the fix and
// the A/B test of that theory.
// ---------------------------------------------------------------------------
__global__ __launch_bounds__(256) void k0_pack(
    const float* __restrict__ W2, unsigned* __restrict__ pk) {
  int col = blockIdx.x * 256 + threadIdx.x;
  if (col >= N_ITEMS) return;
  int row = blockIdx.y;
  float x = W2[(size_t)row * N_ITEMS + col];
  unsigned short hi = bf16_rne(x);
  unsigned short lo = bf16_rne(x - bf16_f(hi));
  int jt = col >> 4, l15 = col & 15;
  int step = row >> 5, rr = row & 31, quad = rr >> 3, j = rr & 7;
  int s = step * 8 + j;
  pk[jt * 1024 + s * 64 + quad * 16 + l15] =
      (unsigned)hi | ((unsigned)lo << 16);
}

// ---------------------------------------------------------------------------
// Kernel 1: S1[c][d] = sum_{i in c} W1[i][d]; counts[c].
// R7: each wave owns 49 CONSECUTIVE rows (12.5 KB contiguous stream) instead
// of a 512KB-strided walk — same stride fix as k3.
// ---------------------------------------------------------------------------
__global__ __launch_bounds__(256) void k1_segsum(
    const int* __restrict__ cl, const float* __restrict__ W1,
    float* __restrict__ S1g, float* __restrict__ cntg) {
  __shared__ float s1[4][N_CLUSTERS][N_D];
  __shared__ float scnt[4][N_CLUSTERS];
  int t = threadIdx.x;
  int wave = t >> 6, lane = t & 63;

  float a[N_CLUSTERS], cn[N_CLUSTERS];
#pragma unroll
  for (int k = 0; k < N_CLUSTERS; ++k) { a[k] = 0.f; cn[k] = 0.f; }

  int gw = blockIdx.x * 4 + wave;              // 0..2047
  int r0 = gw * 49;
  int r1 = min(r0 + 49, N_ITEMS);
  for (int i = r0; i < r1; ++i) {
    int c = cl[i];                             // wave-uniform, sequential
    float w = W1[(size_t)i * N_D + lane];      // contiguous 256B/row stream
#pragma unroll
    for (int k = 0; k < N_CLUSTERS; ++k) {
      bool m = (c == k);
      a[k] += m ? w : 0.f;
      cn[k] += m ? 1.f : 0.f;
    }
  }
#pragma unroll
  for (int k = 0; k < N_CLUSTERS; ++k) s1[wave][k][lane] = a[k];
  if (lane == 0) {
#pragma unroll
    for (int k = 0; k < N_CLUSTERS; ++k) scnt[wave][k] = cn[k];
  }
  __syncthreads();
  const float* fs1 = (const float*)s1;
  for (int i = t; i < N_CLUSTERS * N_D; i += 256) {
    float v = fs1[i] + fs1[640 + i] + fs1[1280 + i] + fs1[1920 + i];
    atomAddF(&S1g[i], v);
  }
  if (t < N_CLUSTERS) {
    float v = scnt[0][t] + scnt[1][t] + scnt[2][t] + scnt[3][t];
    atomAddF(&cntg[t], v);
  }
}

// ---------------------------------------------------------------------------
// Kernel 2: h[row][d] = sum_c input[row][c] * S1[c][d]   (1024 x 64 row-major)
// ---------------------------------------------------------------------------
__global__ __launch_bounds__(256) void k2_h(
    const float* __restrict__ inp, const float* __restrict__ S1g,
    float* __restrict__ h) {
  int idx = blockIdx.x * 256 + threadIdx.x;   // 65536 exactly
  int row = idx >> 6, d = idx & 63;
  float acc = 0.f;
#pragma unroll
  for (int c = 0; c < N_CLUSTERS; ++c)
    acc += inp[row * N_CLUSTERS + c] * S1g[c * N_D + d];
  h[idx] = acc;
}

// ---------------------------------------------------------------------------
// Kernel 2b: build A-operand MFMA fragments of h, split into bf16 hi/lo.
// A layout (16x16x32): lane holds A[m=lane&15][k=(lane>>4)*8 + j], j=0..7.
// ---------------------------------------------------------------------------
__global__ __launch_bounds__(256) void k2b_frag(
    const float* __restrict__ h, short8* __restrict__ hfrag) {
  int id = blockIdx.x * 256 + threadIdx.x;    // 8192 = 64rt * 2ks * 64lane
  int lane = id & 63;
  int ks = (id >> 6) & 1;
  int rt = id >> 7;                            // 0..63
  int row = rt * 16 + (lane & 15);
  int d0 = ks * 32 + (lane >> 4) * 8;
  short8 hi, lo;
#pragma unroll
  for (int j = 0; j < 8; ++j) {
    float x = h[row * N_D + d0 + j];
    unsigned short us = bf16_rne(x);
    hi[j] = (short)us;
    lo[j] = (short)bf16_rne(x - bf16_f(us));
  }
  hfrag[((rt * 2 + ks) * 2 + 0) * 64 + lane] = hi;
  hfrag[((rt * 2 + ks) * 2 + 1) * 64 + lane] = lo;
}

// ---------------------------------------------------------------------------
// Kernel 3 (hot): split-bf16 MFMA logits + exp + LDS bucket accumulation.
// R7: reads the PACKED buffer. Per j-tile: 16 dword loads, each 256B
// contiguous; per wave: 16 consecutive tiles = 64KB contiguous stream.
// Same-by blocks (16 bx values, dispatch-adjacent) reuse each slab via L2/L3.
// MFMA term order identical to R6 (passing numerics).
// ---------------------------------------------------------------------------
__global__ __launch_bounds__(256) void k3_mfma(
    const unsigned* __restrict__ pk, const short8* __restrict__ hfrag,
    const int* __restrict__ cl, float* __restrict__ bucketg) {
  __shared__ float bkt[64][N_CLUSTERS * 4];   // 10240 B
  int t = threadIdx.x;
  int wave = t >> 6, lane = t & 63;
  int l15 = lane & 15;
  int quad = lane >> 4;

  for (int i = t; i < 64 * N_CLUSTERS * 4; i += 256) ((float*)bkt)[i] = 0.f;

  // Resident A-fragments: 4 row-tiles x 2 k-steps x {hi,lo} = 64 VGPRs
  short8 af[4][2][2];
#pragma unroll
  for (int rt = 0; rt < 4; ++rt)
#pragma unroll
    for (int ks = 0; ks < 2; ++ks)
#pragma unroll
      for (int tm = 0; tm < 2; ++tm)
        af[rt][ks][tm] =
            hfrag[(((blockIdx.x * 4 + rt) * 2 + ks) * 2 + tm) * 64 + lane];
  __syncthreads();

  int jt0 = (blockIdx.y * 4 + wave) * 16;     // contiguous 16-tile run

  for (int it = 0; it < 16; ++it) {
    int jt = jt0 + it;
    if (jt >= N_JT) break;

    const unsigned* __restrict__ tp = pk + jt * 1024 + lane;
    unsigned v[16];
#pragma unroll
    for (int s = 0; s < 16; ++s) v[s] = tp[s * 64];   // 16x 256B contiguous

    int cc = cl[jt * 16 + l15];
    int slot = cc * 4 + (lane & 3);

    short8 bh0, bl0, bh1, bl1;
#pragma unroll
    for (int j = 0; j < 8; ++j) {
      bh0[j] = (short)(v[j] & 0xffffu);
      bl0[j] = (short)(v[j] >> 16);
      bh1[j] = (short)(v[8 + j] & 0xffffu);
      bl1[j] = (short)(v[8 + j] >> 16);
    }

#pragma unroll
    for (int rt = 0; rt < 4; ++rt) {
      f32x4 c = {0.f, 0.f, 0.f, 0.f};
      c = __builtin_amdgcn_mfma_f32_16x16x32_bf16(af[rt][0][0], bh0, c, 0, 0, 0);
      c = __builtin_amdgcn_mfma_f32_16x16x32_bf16(af[rt][0][0], bl0, c, 0, 0, 0);
      c = __builtin_amdgcn_mfma_f32_16x16x32_bf16(af[rt][0][1], bh0, c, 0, 0, 0);
      c = __builtin_amdgcn_mfma_f32_16x16x32_bf16(af[rt][1][0], bh1, c, 0, 0, 0);
      c = __builtin_amdgcn_mfma_f32_16x16x32_bf16(af[rt][1][0], bl1, c, 0, 0, 0);
      c = __builtin_amdgcn_mfma_f32_16x16x32_bf16(af[rt][1][1], bh1, c, 0, 0, 0);
      // C/D: col = lane&15 (item), row = quad*4 + reg  [m89-verified]
#pragma unroll
      for (int reg = 0; reg < 4; ++reg)
        atomAddF(&bkt[rt * 16 + quad * 4 + reg][slot], __expf(c[reg]));
    }
  }
  __syncthreads();

  for (int i = t; i < 64 * N_CLUSTERS; i += 256) {
    int r = i / N_CLUSTERS, c = i % N_CLUSTERS;
    float v = bkt[r][c * 4] + bkt[r][c * 4 + 1] + bkt[r][c * 4 + 2] +
              bkt[r][c * 4 + 3];
    atomAddF(&bucketg[(size_t)(blockIdx.x * 64 + r) * N_CLUSTERS + c], v);
  }
}

// ---------------------------------------------------------------------------
// Kernel 4: out[b][c] = bucket[b][c] / (sum_c' bucket[b][c']) / max(cnt[c],1)
// ---------------------------------------------------------------------------
__global__ __launch_bounds__(256) void k4_fin(
    const float* __restrict__ bucketg, const float* __restrict__ cntg,
    float* __restrict__ out) {
  int idx = blockIdx.x * 256 + threadIdx.x;
  if (idx >= N_B * N_CLUSTERS) return;
  int row = idx / N_CLUSTERS, c = idx % N_CLUSTERS;
  const float* b = bucketg + (size_t)row * N_CLUSTERS;
  float total = 0.f;
#pragma unroll
  for (int k = 0; k < N_CLUSTERS; ++k) total += b[k];
  out[idx] = b[c] / (total * fmaxf(cntg[c], 1.f));
}

// ---------------------------------------------------------------------------
// Workspace layout (floats):
//   [0,      640)     S1
//   [640,    650)     counts
//   [1024,   11264)   buckets (1024 x 10)        <- zeroed
//   [12288,  77824)   h (1024 x 64 row-major)
//   [77824,  143360)  hfrag (16384 x short8 = 256 KB)
//   [143360, 6543360) pk (6250 x 1024 words = 25.6 MB packed W2)
// Total ws use: ~26.2 MB.
// ---------------------------------------------------------------------------
extern "C" void kernel_launch(void* const* d_in, const int* in_sizes, int n_in,
                              void* d_out, int out_size, void* d_ws, size_t ws_size,
                              hipStream_t stream) {
  const float* input = (const float*)d_in[0];   // (1024, 10) f32
  const int* cl      = (const int*)d_in[1];     // (100000,) i32
  const float* W1    = (const float*)d_in[2];   // (100000, 64) f32
  const float* W2    = (const float*)d_in[3];   // (64, 100000) f32
  float* out = (float*)d_out;
  float* ws = (float*)d_ws;

  float* S1g     = ws;
  float* cntg    = ws + 640;
  float* bucketg = ws + 1024;
  float* h       = ws + 12288;
  short8* hfrag  = (short8*)(ws + 77824);
  unsigned* pk   = (unsigned*)(ws + 143360);

  hipMemsetAsync(d_ws, 0, (size_t)11264 * sizeof(float), stream);

  dim3 g0((N_ITEMS + 255) / 256, N_D);          // (391, 64)
  k0_pack<<<g0, 256, 0, stream>>>(W2, pk);

  k1_segsum<<<512, 256, 0, stream>>>(cl, W1, S1g, cntg);
  k2_h<<<256, 256, 0, stream>>>(input, S1g, h);
  k2b_frag<<<32, 256, 0, stream>>>(h, hfrag);

  dim3 g3(N_B / 64, GY);   // (16, 98)
  k3_mfma<<<g3, 256, 0, stream>>>(pk, hfrag, cl, bucketg);

  k4_fin<<<(N_B * N_CLUSTERS + 255) / 256, 256, 0, stream>>>(bucketg, cntg, out);
}

// Round 8
// 681.376 us; speedup vs baseline: 1.0545x; 1.0545x over previous
//
#include <hip/hip_runtime.h>
#include <hip/hip_bf16.h>

#define N_B 1024
#define N_ITEMS 100000
#define N_CLUSTERS 10
#define N_D 64
#define N_JT (N_ITEMS / 16)   // 6250 j-tiles of 16 items
#define GYB 196               // j-block dim: 196 blocks * 4 waves * 8 tiles = 6272
#define RUN 8                 // j-tiles per wave (fixed trip count)

typedef __attribute__((ext_vector_type(8))) short short8;
typedef __attribute__((ext_vector_type(4))) float f32x4;

__device__ __forceinline__ void atomAddF(float* p, float v) {
  unsafeAtomicAdd(p, v);
}

// bf16 RNE split helpers (bit-level; sign-safe)
__device__ __forceinline__ unsigned short bf16_rne(float x) {
  unsigned u = __float_as_uint(x);
  u += 0x7FFFu + ((u >> 16) & 1u);
  return (unsigned short)(u >> 16);
}
__device__ __forceinline__ float bf16_f(unsigned short b) {
  return __uint_as_float(((unsigned)b) << 16);
}

// ---------------------------------------------------------------------------
// Kernel 0: stream W2 row-major (contiguous) -> packed split-bf16 buffer in
// k3's exact B-fragment order: pk[jt*1024 + s*64 + quad*16 + l15] = hi|lo<<16,
// s = (row/32)*8 + row%8, quad = (row%32)/8.
// ---------------------------------------------------------------------------
__global__ __launch_bounds__(256) void k0_pack(
    const float* __restrict__ W2, unsigned* __restrict__ pk) {
  int col = blockIdx.x * 256 + threadIdx.x;
  if (col >= N_ITEMS) return;
  int row = blockIdx.y;
  float x = W2[(size_t)row * N_ITEMS + col];
  unsigned short hi = bf16_rne(x);
  unsigned short lo = bf16_rne(x - bf16_f(hi));
  int jt = col >> 4, l15 = col & 15;
  int step = row >> 5, rr = row & 31, quad = rr >> 3, j = rr & 7;
  int s = step * 8 + j;
  pk[jt * 1024 + s * 64 + quad * 16 + l15] =
      (unsigned)hi | ((unsigned)lo << 16);
}

// ---------------------------------------------------------------------------
// Kernel 1: S1[c][d] = sum_{i in c} W1[i][d]; counts[c]. Contiguous per-wave
// row runs (R7 structure).
// ---------------------------------------------------------------------------
__global__ __launch_bounds__(256) void k1_segsum(
    const int* __restrict__ cl, const float* __restrict__ W1,
    float* __restrict__ S1g, float* __restrict__ cntg) {
  __shared__ float s1[4][N_CLUSTERS][N_D];
  __shared__ float scnt[4][N_CLUSTERS];
  int t = threadIdx.x;
  int wave = t >> 6, lane = t & 63;

  float a[N_CLUSTERS], cn[N_CLUSTERS];
#pragma unroll
  for (int k = 0; k < N_CLUSTERS; ++k) { a[k] = 0.f; cn[k] = 0.f; }

  int gw = blockIdx.x * 4 + wave;              // 0..2047
  int r0 = gw * 49;
  int r1 = min(r0 + 49, N_ITEMS);
  for (int i = r0; i < r1; ++i) {
    int c = cl[i];
    float w = W1[(size_t)i * N_D + lane];
#pragma unroll
    for (int k = 0; k < N_CLUSTERS; ++k) {
      bool m = (c == k);
      a[k] += m ? w : 0.f;
      cn[k] += m ? 1.f : 0.f;
    }
  }
#pragma unroll
  for (int k = 0; k < N_CLUSTERS; ++k) s1[wave][k][lane] = a[k];
  if (lane == 0) {
#pragma unroll
    for (int k = 0; k < N_CLUSTERS; ++k) scnt[wave][k] = cn[k];
  }
  __syncthreads();
  const float* fs1 = (const float*)s1;
  for (int i = t; i < N_CLUSTERS * N_D; i += 256) {
    float v = fs1[i] + fs1[640 + i] + fs1[1280 + i] + fs1[1920 + i];
    atomAddF(&S1g[i], v);
  }
  if (t < N_CLUSTERS) {
    float v = scnt[0][t] + scnt[1][t] + scnt[2][t] + scnt[3][t];
    atomAddF(&cntg[t], v);
  }
}

// ---------------------------------------------------------------------------
// Kernel 2: h[row][d] = sum_c input[row][c] * S1[c][d]
// ---------------------------------------------------------------------------
__global__ __launch_bounds__(256) void k2_h(
    const float* __restrict__ inp, const float* __restrict__ S1g,
    float* __restrict__ h) {
  int idx = blockIdx.x * 256 + threadIdx.x;   // 65536 exactly
  int row = idx >> 6, d = idx & 63;
  float acc = 0.f;
#pragma unroll
  for (int c = 0; c < N_CLUSTERS; ++c)
    acc += inp[row * N_CLUSTERS + c] * S1g[c * N_D + d];
  h[idx] = acc;
}

// ---------------------------------------------------------------------------
// Kernel 2b: A-operand MFMA fragments of h, split bf16 hi/lo.
// A layout (16x16x32): lane holds A[m=lane&15][k=(lane>>4)*8 + j].
// ---------------------------------------------------------------------------
__global__ __launch_bounds__(256) void k2b_frag(
    const float* __restrict__ h, short8* __restrict__ hfrag) {
  int id = blockIdx.x * 256 + threadIdx.x;    // 8192
  int lane = id & 63;
  int ks = (id >> 6) & 1;
  int rt = id >> 7;                            // 0..63
  int row = rt * 16 + (lane & 15);
  int d0 = ks * 32 + (lane >> 4) * 8;
  short8 hi, lo;
#pragma unroll
  for (int j = 0; j < 8; ++j) {
    float x = h[row * N_D + d0 + j];
    unsigned short us = bf16_rne(x);
    hi[j] = (short)us;
    lo[j] = (short)bf16_rne(x - bf16_f(us));
  }
  hfrag[((rt * 2 + ks) * 2 + 0) * 64 + lane] = hi;
  hfrag[((rt * 2 + ks) * 2 + 1) * 64 + lane] = lo;
}

// ---------------------------------------------------------------------------
// Kernel 3 (hot): canonical LDS-staged MFMA loop (m97-style; the structure
// the compiler compiles well). A-fragments live in LDS (16 KB, loaded once,
// ds_read_b128 per MFMA operand — lane i reads [i*16,i*16+16): conflict-free).
// Registers hold only: current B-tile v[16], prefetched vn[16], acc f32x4.
// R7 post-mortem: every register-resident-A design compiled to operand
// refetch loops (VGPR=52 vs required 64+) — hence LDS staging.
// ---------------------------------------------------------------------------
__global__ __launch_bounds__(256) void k3_mfma(
    const unsigned* __restrict__ pk, const short8* __restrict__ hfrag,
    const int* __restrict__ cl, float* __restrict__ bucketg) {
  __shared__ short8 afl[16][64];              // 16 KB A-fragments
  __shared__ float bkt[64][N_CLUSTERS * 4];   // 10 KB buckets
  int t = threadIdx.x;
  int wave = t >> 6, lane = t & 63;
  int l15 = lane & 15;
  int quad = lane >> 4;

  for (int i = t; i < 64 * N_CLUSTERS * 4; i += 256) ((float*)bkt)[i] = 0.f;
  // Stage this block's 64-row A-fragment slice: 1024 short8 = 16 KB.
  {
    const short8* src = hfrag + (size_t)blockIdx.x * 1024;
    for (int i = t; i < 1024; i += 256) ((short8*)afl)[i] = src[i];
  }
  __syncthreads();

  int jt0 = (blockIdx.y * 4 + wave) * RUN;

  // ---- software pipeline: prefetch tile it+1 while computing tile it ----
  unsigned v[16];
  int cc;
  {
    int jtc = min(jt0, N_JT - 1);
    const unsigned* tp = pk + jtc * 1024 + lane;
#pragma unroll
    for (int s = 0; s < 16; ++s) v[s] = tp[s * 64];
    cc = cl[jtc * 16 + l15];
  }

#pragma unroll
  for (int it = 0; it < RUN; ++it) {
    int jt = jt0 + it;
    unsigned vn[16];
    int ccn = 0;
    if (it + 1 < RUN) {
      int jtn = min(jt + 1, N_JT - 1);
      const unsigned* tp = pk + jtn * 1024 + lane;
#pragma unroll
      for (int s = 0; s < 16; ++s) vn[s] = tp[s * 64];
      ccn = cl[jtn * 16 + l15];
    }

    bool valid = (jt < N_JT);
    int slot = cc * 4 + (lane & 3);

    short8 bh0, bl0, bh1, bl1;
#pragma unroll
    for (int j = 0; j < 8; ++j) {
      bh0[j] = (short)(v[j] & 0xffffu);
      bl0[j] = (short)(v[j] >> 16);
      bh1[j] = (short)(v[8 + j] & 0xffffu);
      bl1[j] = (short)(v[8 + j] >> 16);
    }

#pragma unroll
    for (int rt = 0; rt < 4; ++rt) {
      // A operands from LDS: one ds_read_b128 each, consumed immediately.
      short8 a00 = afl[rt * 4 + 0][lane];   // [rt][ks=0][hi]
      short8 a01 = afl[rt * 4 + 1][lane];   // [rt][ks=0][lo]
      short8 a10 = afl[rt * 4 + 2][lane];   // [rt][ks=1][hi]
      short8 a11 = afl[rt * 4 + 3][lane];   // [rt][ks=1][lo]
      f32x4 c = {0.f, 0.f, 0.f, 0.f};
      c = __builtin_amdgcn_mfma_f32_16x16x32_bf16(a00, bh0, c, 0, 0, 0);
      c = __builtin_amdgcn_mfma_f32_16x16x32_bf16(a00, bl0, c, 0, 0, 0);
      c = __builtin_amdgcn_mfma_f32_16x16x32_bf16(a01, bh0, c, 0, 0, 0);
      c = __builtin_amdgcn_mfma_f32_16x16x32_bf16(a10, bh1, c, 0, 0, 0);
      c = __builtin_amdgcn_mfma_f32_16x16x32_bf16(a10, bl1, c, 0, 0, 0);
      c = __builtin_amdgcn_mfma_f32_16x16x32_bf16(a11, bh1, c, 0, 0, 0);
      if (valid) {
        // C/D: col = lane&15 (item), row = quad*4 + reg  [m89-verified]
#pragma unroll
        for (int reg = 0; reg < 4; ++reg)
          atomAddF(&bkt[rt * 16 + quad * 4 + reg][slot], __expf(c[reg]));
      }
    }

#pragma unroll
    for (int s = 0; s < 16; ++s) v[s] = vn[s];
    cc = ccn;
  }
  __syncthreads();

  for (int i = t; i < 64 * N_CLUSTERS; i += 256) {
    int r = i / N_CLUSTERS, c = i % N_CLUSTERS;
    float vv = bkt[r][c * 4] + bkt[r][c * 4 + 1] + bkt[r][c * 4 + 2] +
               bkt[r][c * 4 + 3];
    atomAddF(&bucketg[(size_t)(blockIdx.x * 64 + r) * N_CLUSTERS + c], vv);
  }
}

// ---------------------------------------------------------------------------
// Kernel 4: out[b][c] = bucket[b][c] / (sum_c' bucket[b][c']) / max(cnt[c],1)
// ---------------------------------------------------------------------------
__global__ __launch_bounds__(256) void k4_fin(
    const float* __restrict__ bucketg, const float* __restrict__ cntg,
    float* __restrict__ out) {
  int idx = blockIdx.x * 256 + threadIdx.x;
  if (idx >= N_B * N_CLUSTERS) return;
  int row = idx / N_CLUSTERS, c = idx % N_CLUSTERS;
  const float* b = bucketg + (size_t)row * N_CLUSTERS;
  float total = 0.f;
#pragma unroll
  for (int k = 0; k < N_CLUSTERS; ++k) total += b[k];
  out[idx] = b[c] / (total * fmaxf(cntg[c], 1.f));
}

// ---------------------------------------------------------------------------
// Workspace layout (floats):
//   [0,      640)     S1
//   [640,    650)     counts
//   [1024,   11264)   buckets (1024 x 10)        <- zeroed
//   [12288,  77824)   h (1024 x 64)
//   [77824,  143360)  hfrag (16384 x short8 = 256 KB)
//   [143360, 6543360) pk (6250 x 1024 words = 25.6 MB)
// ---------------------------------------------------------------------------
extern "C" void kernel_launch(void* const* d_in, const int* in_sizes, int n_in,
                              void* d_out, int out_size, void* d_ws, size_t ws_size,
                              hipStream_t stream) {
  const float* input = (const float*)d_in[0];   // (1024, 10) f32
  const int* cl      = (const int*)d_in[1];     // (100000,) i32
  const float* W1    = (const float*)d_in[2];   // (100000, 64) f32
  const float* W2    = (const float*)d_in[3];   // (64, 100000) f32
  float* out = (float*)d_out;
  float* ws = (float*)d_ws;

  float* S1g     = ws;
  float* cntg    = ws + 640;
  float* bucketg = ws + 1024;
  float* h       = ws + 12288;
  short8* hfrag  = (short8*)(ws + 77824);
  unsigned* pk   = (unsigned*)(ws + 143360);

  hipMemsetAsync(d_ws, 0, (size_t)11264 * sizeof(float), stream);

  dim3 g0((N_ITEMS + 255) / 256, N_D);          // (391, 64)
  k0_pack<<<g0, 256, 0, stream>>>(W2, pk);

  k1_segsum<<<512, 256, 0, stream>>>(cl, W1, S1g, cntg);
  k2_h<<<256, 256, 0, stream>>>(input, S1g, h);
  k2b_frag<<<32, 256, 0, stream>>>(h, hfrag);

  dim3 g3(N_B / 64, GYB);   // (16, 196)
  k3_mfma<<<g3, 256, 0, stream>>>(pk, hfrag, cl, bucketg);

  k4_fin<<<(N_B * N_CLUSTERS + 255) / 256, 256, 0, stream>>>(bucketg, cntg, out);
}

// Round 9
// 648.616 us; speedup vs baseline: 1.1078x; 1.0505x over previous
//
#include <hip/hip_runtime.h>
#include <hip/hip_bf16.h>

#define N_B 1024
#define N_ITEMS 100000
#define N_CLUSTERS 10
#define N_D 64
#define MAXT 6272            // padded tile capacity (49*4*32), >= NT
#define GYB 49               // j-block dim
#define RUN 32               // tiles per wave: 49*4*32 = 6272 exactly

typedef __attribute__((ext_vector_type(8))) short short8;
typedef __attribute__((ext_vector_type(4))) float f32x4;
typedef __attribute__((ext_vector_type(4))) float float4v;

// bf16 RNE split helpers (bit-level; sign-safe)
__device__ __forceinline__ unsigned short bf16_rne(float x) {
  unsigned u = __float_as_uint(x);
  u += 0x7FFFu + ((u >> 16) & 1u);
  return (unsigned short)(u >> 16);
}
__device__ __forceinline__ float bf16_f(unsigned short b) {
  return __uint_as_float(((unsigned)b) << 16);
}

// ---------------------------------------------------------------------------
// Kernel 1: per-block partial S1 and counts. NO atomics (plain stores).
// 64 blocks x 4 waves, each wave 391 consecutive W1 rows (contiguous stream).
// ---------------------------------------------------------------------------
__global__ __launch_bounds__(256) void k1_segsum(
    const int* __restrict__ cl, const float* __restrict__ W1,
    float* __restrict__ S1p, float* __restrict__ cntp) {
  __shared__ float s1[4][N_CLUSTERS][N_D];
  __shared__ float scnt[4][N_CLUSTERS];
  int t = threadIdx.x;
  int wave = t >> 6, lane = t & 63;

  float a[N_CLUSTERS], cn[N_CLUSTERS];
#pragma unroll
  for (int k = 0; k < N_CLUSTERS; ++k) { a[k] = 0.f; cn[k] = 0.f; }

  int gw = blockIdx.x * 4 + wave;              // 0..255
  int r0 = gw * 391;                           // 256*391 = 100096 >= N_ITEMS
  int r1 = min(r0 + 391, N_ITEMS);
  for (int i = r0; i < r1; ++i) {
    int c = cl[i];
    float w = W1[(size_t)i * N_D + lane];
#pragma unroll
    for (int k = 0; k < N_CLUSTERS; ++k) {
      bool m = (c == k);
      a[k] += m ? w : 0.f;
      cn[k] += m ? 1.f : 0.f;
    }
  }
#pragma unroll
  for (int k = 0; k < N_CLUSTERS; ++k) s1[wave][k][lane] = a[k];
  if (lane == 0) {
#pragma unroll
    for (int k = 0; k < N_CLUSTERS; ++k) scnt[wave][k] = cn[k];
  }
  __syncthreads();
  const float* fs1 = (const float*)s1;
  for (int i = t; i < N_CLUSTERS * N_D; i += 256) {
    S1p[blockIdx.x * 640 + i] =
        fs1[i] + fs1[640 + i] + fs1[1280 + i] + fs1[1920 + i];
  }
  if (t < N_CLUSTERS) {
    cntp[blockIdx.x * N_CLUSTERS + t] =
        scnt[0][t] + scnt[1][t] + scnt[2][t] + scnt[3][t];
  }
}

// ---------------------------------------------------------------------------
// Kernel 1r: single block. Reduce S1/count partials; compute padded segment
// bases (each cluster's segment 16-aligned); fill tileclu[]/nvalid[] tables.
// ---------------------------------------------------------------------------
__global__ __launch_bounds__(256) void k1r(
    const float* __restrict__ S1p, const float* __restrict__ cntp,
    float* __restrict__ S1g, float* __restrict__ cntF, int* __restrict__ meta,
    int* __restrict__ tileclu, int* __restrict__ nvalid) {
  __shared__ int baseS[11];
  __shared__ int cntI[N_CLUSTERS];
  int t = threadIdx.x;
  for (int i = t; i < 640; i += 256) {
    float s = 0.f;
    for (int b = 0; b < 64; ++b) s += S1p[b * 640 + i];
    S1g[i] = s;
  }
  if (t < N_CLUSTERS) {
    float s = 0.f;
    for (int b = 0; b < 64; ++b) s += cntp[b * N_CLUSTERS + t];
    cntF[t] = s;
    cntI[t] = (int)(s + 0.5f);
  }
  __syncthreads();
  if (t == 0) {
    int acc = 0;
    for (int c = 0; c < N_CLUSTERS; ++c) {
      baseS[c] = acc;
      acc += ((cntI[c] + 15) >> 4) << 4;       // pad to multiple of 16
    }
    baseS[10] = acc;
    for (int c = 0; c < 11; ++c) meta[c] = baseS[c];
    meta[11] = acc >> 4;                       // NT
  }
  __syncthreads();
  int NT = baseS[10] >> 4;
  for (int jt = t; jt < MAXT; jt += 256) {
    int c = 0, nv = 0;
    if (jt < NT) {
      int p0 = jt * 16;
      for (int k = 0; k < N_CLUSTERS; ++k)
        if (p0 >= baseS[k] && p0 < baseS[k + 1]) c = k;
      nv = min(16, cntI[c] - (p0 - baseS[c]));
      if (nv < 0) nv = 0;
    }
    tileclu[jt] = c;
    nvalid[jt] = nv;
  }
}

// ---------------------------------------------------------------------------
// Kernel 1c: perm[i] = padded sorted position of item i. Wave-aggregated
// ranking: one int atomicAdd per (wave, cluster-present) — ~15K total.
// ---------------------------------------------------------------------------
__global__ __launch_bounds__(256) void k1c(
    const int* __restrict__ cl, const int* __restrict__ meta,
    int* __restrict__ cursor, int* __restrict__ perm) {
  int i = blockIdx.x * 256 + threadIdx.x;
  int lane = threadIdx.x & 63;
  int c = (i < N_ITEMS) ? cl[i] : -1;
  int pos = 0;
  for (int k = 0; k < N_CLUSTERS; ++k) {
    unsigned long long m = __ballot(c == k);
    if (c == k) {
      int leader = __ffsll((unsigned long long)m) - 1;
      int n = __popcll(m);
      int rank = __popcll(m & ((1ull << lane) - 1ull));
      int base = 0;
      if (lane == leader) base = atomicAdd(&cursor[k], n);
      base = __shfl(base, leader, 64);
      pos = base + rank;
    }
  }
  if (i >= N_ITEMS) return;
  perm[i] = meta[c] + pos;
}

// ---------------------------------------------------------------------------
// Kernel 2: h[row][d] = sum_c input[row][c] * S1[c][d]
// ---------------------------------------------------------------------------
__global__ __launch_bounds__(256) void k2_h(
    const float* __restrict__ inp, const float* __restrict__ S1g,
    float* __restrict__ h) {
  int idx = blockIdx.x * 256 + threadIdx.x;   // 65536 exactly
  int row = idx >> 6, d = idx & 63;
  float acc = 0.f;
#pragma unroll
  for (int c = 0; c < N_CLUSTERS; ++c)
    acc += inp[row * N_CLUSTERS + c] * S1g[c * N_D + d];
  h[idx] = acc;
}

// ---------------------------------------------------------------------------
// Kernel 2b: A-operand MFMA fragments of h, split bf16 hi/lo.
// A layout (16x16x32): lane holds A[m=lane&15][k=(lane>>4)*8 + j].
// ---------------------------------------------------------------------------
__global__ __launch_bounds__(256) void k2b_frag(
    const float* __restrict__ h, short8* __restrict__ hfrag) {
  int id = blockIdx.x * 256 + threadIdx.x;    // 8192
  int lane = id & 63;
  int ks = (id >> 6) & 1;
  int rt = id >> 7;                            // 0..63
  int row = rt * 16 + (lane & 15);
  int d0 = ks * 32 + (lane >> 4) * 8;
  short8 hi, lo;
#pragma unroll
  for (int j = 0; j < 8; ++j) {
    float x = h[row * N_D + d0 + j];
    unsigned short us = bf16_rne(x);
    hi[j] = (short)us;
    lo[j] = (short)bf16_rne(x - bf16_f(us));
  }
  hfrag[((rt * 2 + ks) * 2 + 0) * 64 + lane] = hi;
  hfrag[((rt * 2 + ks) * 2 + 1) * 64 + lane] = lo;
}

// ---------------------------------------------------------------------------
// Kernel 0: pack W2 into sorted split-bf16 B-fragment order. Reads fully
// coalesced row-major; scatter WRITES (fire-and-forget) to sorted positions.
// pk[jt*1024 + s*64 + quad*16 + l15], s=(row/32)*8+row%8, quad=(row%32)/8.
// ---------------------------------------------------------------------------
__global__ __launch_bounds__(256) void k0_pack(
    const float* __restrict__ W2, const int* __restrict__ perm,
    unsigned* __restrict__ pk) {
  int col = blockIdx.x * 256 + threadIdx.x;
  if (col >= N_ITEMS) return;
  int row = blockIdx.y;
  float x = W2[(size_t)row * N_ITEMS + col];
  unsigned short hi = bf16_rne(x);
  unsigned short lo = bf16_rne(x - bf16_f(hi));
  int p = perm[col];
  int jt = p >> 4, l15 = p & 15;
  int step = row >> 5, rr = row & 31, quad = rr >> 3, j = rr & 7;
  int s = step * 8 + j;
  pk[jt * 1024 + s * 64 + quad * 16 + l15] =
      (unsigned)hi | ((unsigned)lo << 16);
}

// ---------------------------------------------------------------------------
// Kernel 3 (hot): ZERO atomics. Tiles are single-cluster (sorted+padded);
// per tile: MFMA -> masked exp -> 16-lane butterfly shfl reduction ->
// exclusively-owned plain LDS read+add+write. Block epilogue: plain stores
// of per-(by) partials; k4 reduces. This is the decisive atomic-theory test.
// ---------------------------------------------------------------------------
__global__ __launch_bounds__(256) void k3_mfma(
    const unsigned* __restrict__ pk, const short8* __restrict__ hfrag,
    const int* __restrict__ tileclu, const int* __restrict__ nvalid,
    float* __restrict__ bucketp) {
  __shared__ short8 afl[16][64];               // 16 KB A-fragments
  __shared__ float bkt[4][64][N_CLUSTERS];     // 10 KB, per-wave exclusive
  int t = threadIdx.x;
  int wave = t >> 6, lane = t & 63;
  int l15 = lane & 15;
  int quad = lane >> 4;

  for (int i = t; i < 4 * 64 * N_CLUSTERS; i += 256) ((float*)&bkt[0][0][0])[i] = 0.f;
  {
    const short8* src = hfrag + (size_t)blockIdx.x * 1024;
    for (int i = t; i < 1024; i += 256) ((short8*)afl)[i] = src[i];
  }
  __syncthreads();

  int jt0 = (blockIdx.y * 4 + wave) * RUN;     // jt0+RUN <= 6272 always

  unsigned v[16];
  int cc, nv;
  {
    const unsigned* tp = pk + jt0 * 1024 + lane;
#pragma unroll
    for (int s = 0; s < 16; ++s) v[s] = tp[s * 64];
    cc = tileclu[jt0];
    nv = nvalid[jt0];
  }

  for (int it = 0; it < RUN; ++it) {
    int jt = jt0 + it;
    unsigned vn[16];
    int ccn = 0, nvn = 0;
    if (it + 1 < RUN) {
      const unsigned* tp = pk + (jt + 1) * 1024 + lane;
#pragma unroll
      for (int s = 0; s < 16; ++s) vn[s] = tp[s * 64];
      ccn = tileclu[jt + 1];
      nvn = nvalid[jt + 1];
    }

    if (nv > 0) {                              // wave-uniform
      short8 bh0, bl0, bh1, bl1;
#pragma unroll
      for (int j = 0; j < 8; ++j) {
        bh0[j] = (short)(v[j] & 0xffffu);
        bl0[j] = (short)(v[j] >> 16);
        bh1[j] = (short)(v[8 + j] & 0xffffu);
        bl1[j] = (short)(v[8 + j] >> 16);
      }
#pragma unroll
      for (int rt = 0; rt < 4; ++rt) {
        short8 a00 = afl[rt * 4 + 0][lane];
        short8 a01 = afl[rt * 4 + 1][lane];
        short8 a10 = afl[rt * 4 + 2][lane];
        short8 a11 = afl[rt * 4 + 3][lane];
        f32x4 c = {0.f, 0.f, 0.f, 0.f};
        c = __builtin_amdgcn_mfma_f32_16x16x32_bf16(a00, bh0, c, 0, 0, 0);
        c = __builtin_amdgcn_mfma_f32_16x16x32_bf16(a00, bl0, c, 0, 0, 0);
        c = __builtin_amdgcn_mfma_f32_16x16x32_bf16(a01, bh0, c, 0, 0, 0);
        c = __builtin_amdgcn_mfma_f32_16x16x32_bf16(a10, bh1, c, 0, 0, 0);
        c = __builtin_amdgcn_mfma_f32_16x16x32_bf16(a10, bl1, c, 0, 0, 0);
        c = __builtin_amdgcn_mfma_f32_16x16x32_bf16(a11, bh1, c, 0, 0, 0);
        // C/D: col=lane&15 (item), row=quad*4+reg  [m89-verified]
        float e0 = (l15 < nv) ? __expf(c[0]) : 0.f;
        float e1 = (l15 < nv) ? __expf(c[1]) : 0.f;
        float e2 = (l15 < nv) ? __expf(c[2]) : 0.f;
        float e3 = (l15 < nv) ? __expf(c[3]) : 0.f;
#pragma unroll
        for (int mstep = 1; mstep < 16; mstep <<= 1) {
          e0 += __shfl_xor(e0, mstep, 64);
          e1 += __shfl_xor(e1, mstep, 64);
          e2 += __shfl_xor(e2, mstep, 64);
          e3 += __shfl_xor(e3, mstep, 64);
        }
        if (l15 == 0) {                        // one owner lane per quad
          int r = rt * 16 + quad * 4;
          bkt[wave][r + 0][cc] += e0;          // plain RMW: exclusive cells
          bkt[wave][r + 1][cc] += e1;
          bkt[wave][r + 2][cc] += e2;
          bkt[wave][r + 3][cc] += e3;
        }
      }
    }

#pragma unroll
    for (int s = 0; s < 16; ++s) v[s] = vn[s];
    cc = ccn;
    nv = nvn;
  }
  __syncthreads();

  for (int i = t; i < 64 * N_CLUSTERS; i += 256) {
    int r = i / N_CLUSTERS, c = i % N_CLUSTERS;
    float s = bkt[0][r][c] + bkt[1][r][c] + bkt[2][r][c] + bkt[3][r][c];
    bucketp[(size_t)blockIdx.y * (N_B * N_CLUSTERS) +
            (size_t)(blockIdx.x * 64 + r) * N_CLUSTERS + c] = s;   // plain store
  }
}

// ---------------------------------------------------------------------------
// Probe: 4 MB copy within pk (unused after k3). Measures in-harness memory
// bandwidth as its own dispatch in rocprof. Fast (~2us) => memory healthy.
// ---------------------------------------------------------------------------
__global__ __launch_bounds__(256) void kp_probe(const float4v* __restrict__ src,
                                                float4v* __restrict__ dst) {
  int i = blockIdx.x * 256 + threadIdx.x;
#pragma unroll
  for (int k = 0; k < 4; ++k) dst[i + k * 65536] = src[i + k * 65536];
}

// ---------------------------------------------------------------------------
// Kernel 4: reduce GYB partials, softmax-normalize, divide by counts.
// Block = 320 threads = 32 rows x 10 clusters; 32 blocks.
// ---------------------------------------------------------------------------
__global__ __launch_bounds__(320) void k4_fin(
    const float* __restrict__ bucketp, const float* __restrict__ cntF,
    float* __restrict__ out) {
  __shared__ float bl[32][N_CLUSTERS];
  int t = threadIdx.x;                         // 0..319
  int r = t / N_CLUSTERS, c = t % N_CLUSTERS;
  int row = blockIdx.x * 32 + r;
  float s = 0.f;
  for (int p = 0; p < GYB; ++p)
    s += bucketp[(size_t)p * (N_B * N_CLUSTERS) + row * N_CLUSTERS + c];
  bl[r][c] = s;
  __syncthreads();
  float tot = 0.f;
#pragma unroll
  for (int k = 0; k < N_CLUSTERS; ++k) tot += bl[r][k];
  out[row * N_CLUSTERS + c] = s / (tot * fmaxf(cntF[c], 1.f));
}

// ---------------------------------------------------------------------------
// Workspace layout (4-byte units):
//   [0,640) S1g | [640,650) cntF | [704,714) cursor(int,zeroed)
//   [768,780) meta(int) | [1024,41984) S1p | [41984,42624) cntp
//   [43008,49280) tileclu | [49280,55552) nvalid | [56320,156320) perm
//   [157696,223232) h | [223232,354304) hfrag (512 KB)
//   [354304,6776832) pk (25.7 MB) | [6776832,7278592) bucketp (2 MB)
// Only [704,784) is zeroed.
// ---------------------------------------------------------------------------
extern "C" void kernel_launch(void* const* d_in, const int* in_sizes, int n_in,
                              void* d_out, int out_size, void* d_ws, size_t ws_size,
                              hipStream_t stream) {
  const float* input = (const float*)d_in[0];   // (1024, 10) f32
  const int* cl      = (const int*)d_in[1];     // (100000,) i32
  const float* W1    = (const float*)d_in[2];   // (100000, 64) f32
  const float* W2    = (const float*)d_in[3];   // (64, 100000) f32
  float* out = (float*)d_out;
  float* ws = (float*)d_ws;

  float* S1g      = ws;
  float* cntF     = ws + 640;
  int*   cursor   = (int*)(ws + 704);
  int*   meta     = (int*)(ws + 768);
  float* S1p      = ws + 1024;
  float* cntp     = ws + 41984;
  int*   tileclu  = (int*)(ws + 43008);
  int*   nvalid   = (int*)(ws + 49280);
  int*   perm     = (int*)(ws + 56320);
  float* h        = ws + 157696;
  short8* hfrag   = (short8*)(ws + 223232);
  unsigned* pk    = (unsigned*)(ws + 354304);
  float* bucketp  = ws + 6776832;

  hipMemsetAsync(ws + 704, 0, 80 * sizeof(int), stream);

  k1_segsum<<<64, 256, 0, stream>>>(cl, W1, S1p, cntp);
  k1r<<<1, 256, 0, stream>>>(S1p, cntp, S1g, cntF, meta, tileclu, nvalid);
  k1c<<<391, 256, 0, stream>>>(cl, meta, cursor, perm);
  k2_h<<<256, 256, 0, stream>>>(input, S1g, h);
  k2b_frag<<<32, 256, 0, stream>>>(h, hfrag);

  dim3 g0((N_ITEMS + 255) / 256, N_D);          // (391, 64)
  k0_pack<<<g0, 256, 0, stream>>>(W2, perm, pk);

  dim3 g3(N_B / 64, GYB);                       // (16, 49)
  k3_mfma<<<g3, 256, 0, stream>>>(pk, hfrag, tileclu, nvalid, bucketp);

  kp_probe<<<256, 256, 0, stream>>>((const float4v*)pk,
                                    (float4v*)(pk + 4194304));

  k4_fin<<<32, 320, 0, stream>>>(bucketp, cntF, out);
}

// Round 10
// 385.668 us; speedup vs baseline: 1.8630x; 1.6818x over previous
//
#include <hip/hip_runtime.h>
#include <hip/hip_bf16.h>

#define N_B 1024
#define N_ITEMS 100000
#define N_CLUSTERS 10
#define N_D 64
#define MAXT 6272            // padded tile capacity; NT <= 6260 always
#define GYB 49               // k3 j-block dim
#define RUN 32               // tiles per wave: 49*4*32 = 6272 exactly
#define K1B 392              // k1 blocks: 392*4 waves*64 rows = 100352

typedef __attribute__((ext_vector_type(8))) short short8;
typedef __attribute__((ext_vector_type(4))) float f32x4;

// bf16 RNE split helpers (bit-level; sign-safe)
__device__ __forceinline__ unsigned short bf16_rne(float x) {
  unsigned u = __float_as_uint(x);
  u += 0x7FFFu + ((u >> 16) & 1u);
  return (unsigned short)(u >> 16);
}
__device__ __forceinline__ float bf16_f(unsigned short b) {
  return __uint_as_float(((unsigned)b) << 16);
}

// ---------------------------------------------------------------------------
// Kernel 1: per-block partial S1/counts. R10: 392 blocks (vs R9's 64 — the
// 210us latency wall), 64 rows/wave, batches of 8 independent loads (MLP 8).
// ---------------------------------------------------------------------------
__global__ __launch_bounds__(256) void k1_segsum(
    const int* __restrict__ cl, const float* __restrict__ W1,
    float* __restrict__ S1p, float* __restrict__ cntp) {
  __shared__ float s1[4][N_CLUSTERS][N_D];
  __shared__ float scnt[4][N_CLUSTERS];
  int t = threadIdx.x;
  int wave = t >> 6, lane = t & 63;

  float a[N_CLUSTERS], cn[N_CLUSTERS];
#pragma unroll
  for (int k = 0; k < N_CLUSTERS; ++k) { a[k] = 0.f; cn[k] = 0.f; }

  int gw = blockIdx.x * 4 + wave;              // 0..1567
  int r0 = gw * 64;
#pragma unroll 1
  for (int b = 0; b < 8; ++b) {
    int i0 = r0 + b * 8;
    float w[8];
    int c[8];
    if (i0 + 8 <= N_ITEMS) {
#pragma unroll
      for (int j = 0; j < 8; ++j) {
        c[j] = cl[i0 + j];                     // wave-uniform -> s_load
        w[j] = W1[(size_t)(i0 + j) * N_D + lane];  // 8 independent 256B loads
      }
    } else {
#pragma unroll
      for (int j = 0; j < 8; ++j) {
        int i = i0 + j;
        bool ok = i < N_ITEMS;
        c[j] = ok ? cl[i] : -1;
        w[j] = ok ? W1[(size_t)i * N_D + lane] : 0.f;
      }
    }
#pragma unroll
    for (int j = 0; j < 8; ++j)
#pragma unroll
      for (int k = 0; k < N_CLUSTERS; ++k) {
        bool m = (c[j] == k);
        a[k] += m ? w[j] : 0.f;
        cn[k] += m ? 1.f : 0.f;
      }
  }
#pragma unroll
  for (int k = 0; k < N_CLUSTERS; ++k) s1[wave][k][lane] = a[k];
  if (lane == 0) {
#pragma unroll
    for (int k = 0; k < N_CLUSTERS; ++k) scnt[wave][k] = cn[k];
  }
  __syncthreads();
  const float* fs1 = (const float*)s1;
  for (int i = t; i < N_CLUSTERS * N_D; i += 256) {
    S1p[blockIdx.x * 640 + i] =
        fs1[i] + fs1[640 + i] + fs1[1280 + i] + fs1[1920 + i];
  }
  if (t < N_CLUSTERS) {
    cntp[blockIdx.x * N_CLUSTERS + t] =
        scnt[0][t] + scnt[1][t] + scnt[2][t] + scnt[3][t];
  }
}

// ---------------------------------------------------------------------------
// Kernel 1r: single block. Reduce partials; padded segment bases; tile
// tables; zero cursors (replaces memset launch); fill inv[] pad slots.
// ---------------------------------------------------------------------------
__global__ __launch_bounds__(256) void k1r(
    const float* __restrict__ S1p, const float* __restrict__ cntp,
    float* __restrict__ S1g, float* __restrict__ cntF, int* __restrict__ meta,
    int* __restrict__ tileclu, int* __restrict__ nvalid,
    int* __restrict__ inv, int* __restrict__ cursor) {
  __shared__ int baseS[11];
  __shared__ int cntI[N_CLUSTERS];
  int t = threadIdx.x;
  if (t < 16) cursor[t] = 0;
  for (int i = t; i < 640; i += 256) {
    float s = 0.f;
    for (int b = 0; b < K1B; ++b) s += S1p[b * 640 + i];   // independent loads
    S1g[i] = s;
  }
  if (t < N_CLUSTERS) {
    float s = 0.f;
    for (int b = 0; b < K1B; ++b) s += cntp[b * N_CLUSTERS + t];
    cntF[t] = s;
    cntI[t] = (int)(s + 0.5f);
  }
  __syncthreads();
  if (t == 0) {
    int acc = 0;
    for (int c = 0; c < N_CLUSTERS; ++c) {
      baseS[c] = acc;
      acc += ((cntI[c] + 15) >> 4) << 4;       // 16-align each segment
    }
    baseS[10] = acc;
    for (int c = 0; c < 11; ++c) meta[c] = baseS[c];
    meta[11] = acc >> 4;                       // NT
  }
  __syncthreads();
  int NT = baseS[10] >> 4;
  for (int jt = t; jt < MAXT; jt += 256) {
    int c = 0, nv = 0;
    if (jt < NT) {
      int p0 = jt * 16;
      for (int k = 0; k < N_CLUSTERS; ++k)
        if (p0 >= baseS[k] && p0 < baseS[k + 1]) c = k;
      nv = min(16, cntI[c] - (p0 - baseS[c]));
      if (nv < 0) nv = 0;
    }
    tileclu[jt] = c;
    nvalid[jt] = nv;
  }
  int end = baseS[10];
  for (int p = t; p < end; p += 256) {         // fill pad slots with item 0
    int c = 0;
    for (int k = 0; k < N_CLUSTERS; ++k)
      if (p >= baseS[k] && p < baseS[k + 1]) c = k;
    if (p - baseS[c] >= cntI[c]) inv[p] = 0;
  }
}

// ---------------------------------------------------------------------------
// Kernel 1c: inverse perm (pos -> item), block-aggregated ranking.
// Only ~3.9K int atomics total (one per block per cluster).
// ---------------------------------------------------------------------------
__global__ __launch_bounds__(256) void k1c(
    const int* __restrict__ cl, const int* __restrict__ meta,
    int* __restrict__ cursor, int* __restrict__ inv) {
  __shared__ int wn[4][N_CLUSTERS];
  __shared__ int bb[N_CLUSTERS];
  int i = blockIdx.x * 256 + threadIdx.x;
  int wave = threadIdx.x >> 6, lane = threadIdx.x & 63;
  int c = (i < N_ITEMS) ? cl[i] : -1;
  unsigned long long m[N_CLUSTERS];
#pragma unroll
  for (int k = 0; k < N_CLUSTERS; ++k) {
    m[k] = __ballot(c == k);
    if (lane == 0) wn[wave][k] = __popcll(m[k]);
  }
  __syncthreads();
  if (threadIdx.x < N_CLUSTERS) {
    int tot = wn[0][threadIdx.x] + wn[1][threadIdx.x] + wn[2][threadIdx.x] +
              wn[3][threadIdx.x];
    bb[threadIdx.x] = tot ? atomicAdd(&cursor[threadIdx.x], tot) : 0;
  }
  __syncthreads();
  if (c >= 0) {
    int rank = 0;
#pragma unroll
    for (int k = 0; k < N_CLUSTERS; ++k)
      if (c == k) rank = __popcll(m[k] & ((1ull << lane) - 1ull));
    int wsum = 0;
    for (int w2 = 0; w2 < wave; ++w2) wsum += wn[w2][c];
    inv[meta[c] + bb[c] + wsum + rank] = i;
  }
}

// ---------------------------------------------------------------------------
// Kernel 2: h[row][d] = sum_c input[row][c] * S1[c][d]
// ---------------------------------------------------------------------------
__global__ __launch_bounds__(256) void k2_h(
    const float* __restrict__ inp, const float* __restrict__ S1g,
    float* __restrict__ h) {
  int idx = blockIdx.x * 256 + threadIdx.x;   // 65536 exactly
  int row = idx >> 6, d = idx & 63;
  float acc = 0.f;
#pragma unroll
  for (int c = 0; c < N_CLUSTERS; ++c)
    acc += inp[row * N_CLUSTERS + c] * S1g[c * N_D + d];
  h[idx] = acc;
}

// ---------------------------------------------------------------------------
// Kernel 2b: A-operand MFMA fragments of h, split bf16 hi/lo.
// A layout (16x16x32): lane holds A[m=lane&15][k=(lane>>4)*8 + j].
// ---------------------------------------------------------------------------
__global__ __launch_bounds__(256) void k2b_frag(
    const float* __restrict__ h, short8* __restrict__ hfrag) {
  int id = blockIdx.x * 256 + threadIdx.x;    // 8192
  int lane = id & 63;
  int ks = (id >> 6) & 1;
  int rt = id >> 7;                            // 0..63
  int row = rt * 16 + (lane & 15);
  int d0 = ks * 32 + (lane >> 4) * 8;
  short8 hi, lo;
#pragma unroll
  for (int j = 0; j < 8; ++j) {
    float x = h[row * N_D + d0 + j];
    unsigned short us = bf16_rne(x);
    hi[j] = (short)us;
    lo[j] = (short)bf16_rne(x - bf16_f(us));
  }
  hfrag[((rt * 2 + ks) * 2 + 0) * 64 + lane] = hi;
  hfrag[((rt * 2 + ks) * 2 + 1) * 64 + lane] = lo;
}

// ---------------------------------------------------------------------------
// Kernel 0 (R10: gather version). One block per tile; 16 source cols staged
// in LDS; reads W2 scattered (L3-resident, 25.6 MB) but WRITES pk perfectly
// coalesced. Replaces R9's scatter-write pack.
// ---------------------------------------------------------------------------
__global__ __launch_bounds__(256) void k0_pack(
    const float* __restrict__ W2, const int* __restrict__ inv,
    const int* __restrict__ meta, unsigned* __restrict__ pk) {
  __shared__ int cols[16];
  int jt = blockIdx.x;
  if (jt >= meta[11]) return;                  // NT
  int t = threadIdx.x;
  if (t < 16) cols[t] = inv[jt * 16 + t];
  __syncthreads();
#pragma unroll
  for (int k = 0; k < 4; ++k) {
    int w = t + k * 256;                       // word within tile, 0..1023
    int s = w >> 6, quad = (w >> 4) & 3, l15 = w & 15;
    int row = (s >> 3) * 32 + quad * 8 + (s & 7);
    int col = cols[l15];
    float x = W2[(size_t)row * N_ITEMS + col];
    unsigned short hi = bf16_rne(x);
    unsigned short lo = bf16_rne(x - bf16_f(hi));
    pk[jt * 1024 + w] = (unsigned)hi | ((unsigned)lo << 16);
  }
}

// ---------------------------------------------------------------------------
// Kernel 3 (hot): zero-atomic MFMA (R9 structure, unchanged — it dropped
// below 208us there). Single-cluster tiles; shfl-reduce; exclusive LDS cells;
// plain partial stores.
// ---------------------------------------------------------------------------
__global__ __launch_bounds__(256) void k3_mfma(
    const unsigned* __restrict__ pk, const short8* __restrict__ hfrag,
    const int* __restrict__ tileclu, const int* __restrict__ nvalid,
    float* __restrict__ bucketp) {
  __shared__ short8 afl[16][64];               // 16 KB A-fragments
  __shared__ float bkt[4][64][N_CLUSTERS];     // 10 KB, per-wave exclusive
  int t = threadIdx.x;
  int wave = t >> 6, lane = t & 63;
  int l15 = lane & 15;
  int quad = lane >> 4;

  for (int i = t; i < 4 * 64 * N_CLUSTERS; i += 256)
    ((float*)&bkt[0][0][0])[i] = 0.f;
  {
    const short8* src = hfrag + (size_t)blockIdx.x * 1024;
    for (int i = t; i < 1024; i += 256) ((short8*)afl)[i] = src[i];
  }
  __syncthreads();

  int jt0 = (blockIdx.y * 4 + wave) * RUN;     // jt0+RUN <= 6272 always

  unsigned v[16];
  int cc, nv;
  {
    const unsigned* tp = pk + jt0 * 1024 + lane;
#pragma unroll
    for (int s = 0; s < 16; ++s) v[s] = tp[s * 64];
    cc = tileclu[jt0];
    nv = nvalid[jt0];
  }

  for (int it = 0; it < RUN; ++it) {
    int jt = jt0 + it;
    unsigned vn[16];
    int ccn = 0, nvn = 0;
    if (it + 1 < RUN) {
      const unsigned* tp = pk + (jt + 1) * 1024 + lane;
#pragma unroll
      for (int s = 0; s < 16; ++s) vn[s] = tp[s * 64];
      ccn = tileclu[jt + 1];
      nvn = nvalid[jt + 1];
    }

    if (nv > 0) {                              // wave-uniform
      short8 bh0, bl0, bh1, bl1;
#pragma unroll
      for (int j = 0; j < 8; ++j) {
        bh0[j] = (short)(v[j] & 0xffffu);
        bl0[j] = (short)(v[j] >> 16);
        bh1[j] = (short)(v[8 + j] & 0xffffu);
        bl1[j] = (short)(v[8 + j] >> 16);
      }
#pragma unroll
      for (int rt = 0; rt < 4; ++rt) {
        short8 a00 = afl[rt * 4 + 0][lane];
        short8 a01 = afl[rt * 4 + 1][lane];
        short8 a10 = afl[rt * 4 + 2][lane];
        short8 a11 = afl[rt * 4 + 3][lane];
        f32x4 c = {0.f, 0.f, 0.f, 0.f};
        c = __builtin_amdgcn_mfma_f32_16x16x32_bf16(a00, bh0, c, 0, 0, 0);
        c = __builtin_amdgcn_mfma_f32_16x16x32_bf16(a00, bl0, c, 0, 0, 0);
        c = __builtin_amdgcn_mfma_f32_16x16x32_bf16(a01, bh0, c, 0, 0, 0);
        c = __builtin_amdgcn_mfma_f32_16x16x32_bf16(a10, bh1, c, 0, 0, 0);
        c = __builtin_amdgcn_mfma_f32_16x16x32_bf16(a10, bl1, c, 0, 0, 0);
        c = __builtin_amdgcn_mfma_f32_16x16x32_bf16(a11, bh1, c, 0, 0, 0);
        // C/D: col=lane&15 (item), row=quad*4+reg  [m89-verified]
        float e0 = (l15 < nv) ? __expf(c[0]) : 0.f;
        float e1 = (l15 < nv) ? __expf(c[1]) : 0.f;
        float e2 = (l15 < nv) ? __expf(c[2]) : 0.f;
        float e3 = (l15 < nv) ? __expf(c[3]) : 0.f;
#pragma unroll
        for (int mstep = 1; mstep < 16; mstep <<= 1) {
          e0 += __shfl_xor(e0, mstep, 64);
          e1 += __shfl_xor(e1, mstep, 64);
          e2 += __shfl_xor(e2, mstep, 64);
          e3 += __shfl_xor(e3, mstep, 64);
        }
        if (l15 == 0) {                        // exclusive (wave,row) cells
          int r = rt * 16 + quad * 4;
          bkt[wave][r + 0][cc] += e0;
          bkt[wave][r + 1][cc] += e1;
          bkt[wave][r + 2][cc] += e2;
          bkt[wave][r + 3][cc] += e3;
        }
      }
    }

#pragma unroll
    for (int s = 0; s < 16; ++s) v[s] = vn[s];
    cc = ccn;
    nv = nvn;
  }
  __syncthreads();

  for (int i = t; i < 64 * N_CLUSTERS; i += 256) {
    int r = i / N_CLUSTERS, c = i % N_CLUSTERS;
    float s = bkt[0][r][c] + bkt[1][r][c] + bkt[2][r][c] + bkt[3][r][c];
    bucketp[(size_t)blockIdx.y * (N_B * N_CLUSTERS) +
            (size_t)(blockIdx.x * 64 + r) * N_CLUSTERS + c] = s;
  }
}

// ---------------------------------------------------------------------------
// Kernel 4: reduce GYB partials, normalize, divide by counts.
// ---------------------------------------------------------------------------
__global__ __launch_bounds__(320) void k4_fin(
    const float* __restrict__ bucketp, const float* __restrict__ cntF,
    float* __restrict__ out) {
  __shared__ float bl[32][N_CLUSTERS];
  int t = threadIdx.x;                         // 0..319
  int r = t / N_CLUSTERS, c = t % N_CLUSTERS;
  int row = blockIdx.x * 32 + r;
  float s = 0.f;
  for (int p = 0; p < GYB; ++p)
    s += bucketp[(size_t)p * (N_B * N_CLUSTERS) + row * N_CLUSTERS + c];
  bl[r][c] = s;
  __syncthreads();
  float tot = 0.f;
#pragma unroll
  for (int k = 0; k < N_CLUSTERS; ++k) tot += bl[r][k];
  out[row * N_CLUSTERS + c] = s / (tot * fmaxf(cntF[c], 1.f));
}

// ---------------------------------------------------------------------------
// Workspace layout (4-byte units), total 28.7 MB:
//   [0,640) S1g | [640,650) cntF | [656,668) meta | [672,688) cursor
//   [1024,7296) tileclu | [7296,13568) nvalid | [16384,116736) inv
//   [116736,247808) hfrag | [247808,6670336) pk
//   scratch (dead after k2b/k1r): [6670336,6735872) h |
//     [6735872,6986752) S1p | [6986752,6990672) cntp
//   bucketp OVERLAYS scratch: [6670336,7172096)  (written in k3, after all
//   scratch readers are done; stream-ordered)
// No memset needed: cursor zeroed by k1r; everything else fully written.
// ---------------------------------------------------------------------------
extern "C" void kernel_launch(void* const* d_in, const int* in_sizes, int n_in,
                              void* d_out, int out_size, void* d_ws, size_t ws_size,
                              hipStream_t stream) {
  const float* input = (const float*)d_in[0];   // (1024, 10) f32
  const int* cl      = (const int*)d_in[1];     // (100000,) i32
  const float* W1    = (const float*)d_in[2];   // (100000, 64) f32
  const float* W2    = (const float*)d_in[3];   // (64, 100000) f32
  float* out = (float*)d_out;
  float* ws = (float*)d_ws;

  float* S1g      = ws;
  float* cntF     = ws + 640;
  int*   meta     = (int*)(ws + 656);
  int*   cursor   = (int*)(ws + 672);
  int*   tileclu  = (int*)(ws + 1024);
  int*   nvalid   = (int*)(ws + 7296);
  int*   inv      = (int*)(ws + 16384);
  short8* hfrag   = (short8*)(ws + 116736);
  unsigned* pk    = (unsigned*)(ws + 247808);
  float* h        = ws + 6670336;
  float* S1p      = ws + 6735872;
  float* cntp     = ws + 6986752;
  float* bucketp  = ws + 6670336;              // overlays h/S1p/cntp (dead)

  k1_segsum<<<K1B, 256, 0, stream>>>(cl, W1, S1p, cntp);
  k1r<<<1, 256, 0, stream>>>(S1p, cntp, S1g, cntF, meta, tileclu, nvalid,
                             inv, cursor);
  k1c<<<391, 256, 0, stream>>>(cl, meta, cursor, inv);
  k2_h<<<256, 256, 0, stream>>>(input, S1g, h);
  k2b_frag<<<32, 256, 0, stream>>>(h, hfrag);

  k0_pack<<<MAXT, 256, 0, stream>>>(W2, inv, meta, pk);

  dim3 g3(N_B / 64, GYB);                       // (16, 49)
  k3_mfma<<<g3, 256, 0, stream>>>(pk, hfrag, tileclu, nvalid, bucketp);

  k4_fin<<<32, 320, 0, stream>>>(bucketp, cntF, out);
}